// Round 1
// baseline (1845.997 us; speedup 1.0000x reference)
//
#include <hip/hip_runtime.h>
#include <cstdint>
#include <math.h>

// ---------------- workspace layout (float offsets) ----------------
#define WS_RAW     0ull                 // 3136*2048           raw conv out [m][oc]
#define WS_Y1P     6422528ull           // 16*3136*128         nav1 partials (aliased by pconv later)
#define WS_Y1      12845056ull          // 3136*128
#define WS_Y2      13246464ull          // 784*128
#define WS_Y3      13346816ull          // 256*128
#define WS_SCORES  13379584ull          // 16*1614
#define WS_WT2     13405408ull          // 147456
#define WS_WT3     13552864ull          // 147456
#define WS_CONCAT  13700320ull          // 16*10240
#define WS_TOPIDX  13864160ull          // 64 ints
#define WS_PART    13864224ull          // 64*3*224*224
#define WS_PCONV   WS_Y1P               // 3136*2048 (alias; y1p dead by then)

// ---------------- patchify conv as GEMM ----------------
// C[m][n] = sum_k A[m][k]*W[n][k] + bias[n]
// SRC=0: A from x (16,3,448,448), positions 14x14, patch 32x32 -> k=c*1024+r*32+cc
// SRC=1: A from part (64,3,224,224), positions 7x7
template <int SRC>
__global__ __launch_bounds__(256)
void patch_gemm(const float* __restrict__ img, const float* __restrict__ w,
                const float* __restrict__ bias, float* __restrict__ out)
{
    constexpr int H  = SRC ? 224 : 448;
    constexpr int WO = SRC ? 7 : 14;
    constexpr int P  = WO * WO;
    const int M = 3136;
    const int mt = blockIdx.x, nt = blockIdx.y;
    const int tid = threadIdx.x;
    __shared__ float As[16][128];
    __shared__ float Bs[16][128];
    float acc[8][8] = {};
    const int tx = tid % 16, ty = tid / 16;
    const int lr = tid % 128;            // staging row (A: m-row, B: n-row)
    const int lk = (tid / 128) * 8;      // staging k offset (0 or 8)

    const int am = mt * 128 + lr;
    const int ab  = am / P;
    const int apos = am % P;
    const int aoy = apos / WO, aox = apos % WO;
    const int bn = nt * 128 + lr;        // < 2048 always

    for (int k0 = 0; k0 < 3072; k0 += 16) {
        // stage A (two float4 along k; 8 consecutive k stay in one 32-px row)
        {
            const int kg = k0 + lk;
            const int c = kg >> 10, rr = (kg & 1023) >> 5, cc = kg & 31;
            float4 v0, v1;
            if (am < M) {
                const float* p = img + (size_t)(((ab * 3 + c) * H + aoy * 32 + rr) * H + aox * 32 + cc);
                v0 = *(const float4*)p; v1 = *(const float4*)(p + 4);
            } else {
                v0 = make_float4(0.f, 0.f, 0.f, 0.f); v1 = v0;
            }
            As[lk + 0][lr] = v0.x; As[lk + 1][lr] = v0.y; As[lk + 2][lr] = v0.z; As[lk + 3][lr] = v0.w;
            As[lk + 4][lr] = v1.x; As[lk + 5][lr] = v1.y; As[lk + 6][lr] = v1.z; As[lk + 7][lr] = v1.w;
        }
        // stage B
        {
            const int kg = k0 + lk;
            const float* p = w + (size_t)bn * 3072 + kg;
            float4 v0 = *(const float4*)p, v1 = *(const float4*)(p + 4);
            Bs[lk + 0][lr] = v0.x; Bs[lk + 1][lr] = v0.y; Bs[lk + 2][lr] = v0.z; Bs[lk + 3][lr] = v0.w;
            Bs[lk + 4][lr] = v1.x; Bs[lk + 5][lr] = v1.y; Bs[lk + 6][lr] = v1.z; Bs[lk + 7][lr] = v1.w;
        }
        __syncthreads();
        #pragma unroll
        for (int kk = 0; kk < 16; ++kk) {
            float a[8], b[8];
            *(float4*)&a[0] = *(const float4*)&As[kk][ty * 8];
            *(float4*)&a[4] = *(const float4*)&As[kk][ty * 8 + 4];
            *(float4*)&b[0] = *(const float4*)&Bs[kk][tx * 8];
            *(float4*)&b[4] = *(const float4*)&Bs[kk][tx * 8 + 4];
            #pragma unroll
            for (int i = 0; i < 8; ++i)
                #pragma unroll
                for (int j = 0; j < 8; ++j)
                    acc[i][j] += a[i] * b[j];
        }
        __syncthreads();
    }
    #pragma unroll
    for (int i = 0; i < 8; ++i) {
        const int m = mt * 128 + ty * 8 + i;
        if (m < M) {
            float* po = out + (size_t)m * 2048 + nt * 128 + tx * 8;
            const float* bp = bias + nt * 128 + tx * 8;
            #pragma unroll
            for (int j = 0; j < 8; ++j) po[j] = acc[i][j] + bp[j];
        }
    }
}

// ---------------- navigator conv1 as K-split GEMM ----------------
// in raw [3136][2048] (m=(b,pos14)), w (128,2048,3,3) => B[n][k], k=ic*9+tap, K=18432 split 16x1152
__global__ __launch_bounds__(256)
void nav1_gemm(const float* __restrict__ raw, const float* __restrict__ w,
               float* __restrict__ y1p)
{
    const int mt = blockIdx.x;   // 25
    const int ks = blockIdx.y;   // 16
    const int tid = threadIdx.x;
    __shared__ float As[16][128];
    __shared__ float Bs[16][128];
    float acc[8][8] = {};
    const int tx = tid % 16, ty = tid / 16;
    const int lr = tid % 128, lk = (tid / 128) * 8;

    const int am = mt * 128 + lr;
    const int ab = am / 196, apos = am % 196;
    const int aoy = apos / 14, aox = apos % 14;
    const int kbase = ks * 1152;

    for (int kt = 0; kt < 1152; kt += 16) {
        // stage A: scalar gathers with halo guard
        #pragma unroll
        for (int i = 0; i < 8; ++i) {
            const int kg = kbase + kt + lk + i;
            const int ic = kg / 9, tap = kg - ic * 9;
            const int iy = aoy + tap / 3 - 1, ix = aox + (tap % 3) - 1;
            float v = 0.f;
            if (am < 3136 && iy >= 0 && iy < 14 && ix >= 0 && ix < 14)
                v = raw[(size_t)(ab * 196 + iy * 14 + ix) * 2048 + ic];
            As[lk + i][lr] = v;
        }
        // stage B (contiguous k)
        {
            const int kg = kbase + kt + lk;
            const float* p = w + (size_t)lr * 18432 + kg;
            float4 v0 = *(const float4*)p, v1 = *(const float4*)(p + 4);
            Bs[lk + 0][lr] = v0.x; Bs[lk + 1][lr] = v0.y; Bs[lk + 2][lr] = v0.z; Bs[lk + 3][lr] = v0.w;
            Bs[lk + 4][lr] = v1.x; Bs[lk + 5][lr] = v1.y; Bs[lk + 6][lr] = v1.z; Bs[lk + 7][lr] = v1.w;
        }
        __syncthreads();
        #pragma unroll
        for (int kk = 0; kk < 16; ++kk) {
            float a[8], b[8];
            *(float4*)&a[0] = *(const float4*)&As[kk][ty * 8];
            *(float4*)&a[4] = *(const float4*)&As[kk][ty * 8 + 4];
            *(float4*)&b[0] = *(const float4*)&Bs[kk][tx * 8];
            *(float4*)&b[4] = *(const float4*)&Bs[kk][tx * 8 + 4];
            #pragma unroll
            for (int i = 0; i < 8; ++i)
                #pragma unroll
                for (int j = 0; j < 8; ++j)
                    acc[i][j] += a[i] * b[j];
        }
        __syncthreads();
    }
    #pragma unroll
    for (int i = 0; i < 8; ++i) {
        const int m = mt * 128 + ty * 8 + i;
        if (m < 3136) {
            float* po = y1p + ((size_t)ks * 3136 + m) * 128 + tx * 8;
            #pragma unroll
            for (int j = 0; j < 8; ++j) po[j] = acc[i][j];
        }
    }
}

__global__ __launch_bounds__(256)
void y1_reduce(const float* __restrict__ y1p, const float* __restrict__ bias,
               float* __restrict__ y1)
{
    const int t = blockIdx.x * 256 + threadIdx.x;
    if (t >= 3136 * 128) return;
    const int n = t & 127;
    float s = bias[n];
    #pragma unroll
    for (int ks = 0; ks < 16; ++ks) s += y1p[(size_t)ks * 3136 * 128 + t];
    y1[t] = fmaxf(s, 0.f);
}

// ---------------- 1x1 "tidy" convs -> scores (wave per output) ----------------
__global__ __launch_bounds__(256)
void tidy(const float* __restrict__ in, const float* __restrict__ w,
          const float* __restrict__ bias, float* __restrict__ scores,
          int P, int nch, int off)
{
    const int wid = (blockIdx.x * 256 + threadIdx.x) >> 6;
    const int lane = threadIdx.x & 63;
    const int total = 16 * nch * P;
    if (wid >= total) return;
    const int pos = wid % P, ch = (wid / P) % nch, b = wid / (P * nch);
    const float* r = in + (size_t)(b * P + pos) * 128;
    const float* wr = w + ch * 128;
    float acc = r[lane] * wr[lane] + r[lane + 64] * wr[lane + 64];
    #pragma unroll
    for (int s = 32; s > 0; s >>= 1) acc += __shfl_down(acc, s, 64);
    if (lane == 0) scores[b * 1614 + off + ch * P + pos] = acc + bias[ch];
}

// ---------------- weight transpose for strided convs ----------------
__global__ __launch_bounds__(256)
void wtrans(const float* __restrict__ w, float* __restrict__ wt)
{
    const int t = blockIdx.x * 256 + threadIdx.x;
    if (t >= 147456) return;
    const int oc = t / 1152, r = t % 1152;
    wt[r * 128 + oc] = w[t];
}

// ---------------- 3x3 stride-2 conv, 128->128, relu ----------------
__global__ __launch_bounds__(256)
void conv_s2(const float* __restrict__ in, const float* __restrict__ wt,
             const float* __restrict__ bias, float* __restrict__ out,
             int Win, int Wout)
{
    const int t = blockIdx.x * 256 + threadIdx.x;
    const int oc = t & 127;
    const int pos = (t >> 7) % (Wout * Wout);
    const int b = t / (128 * Wout * Wout);
    if (b >= 16) return;
    const int oy = pos / Wout, ox = pos % Wout;
    float acc = bias[oc];
    for (int dy = 0; dy < 3; ++dy) {
        const int y = oy * 2 + dy - 1;
        if (y < 0 || y >= Win) continue;
        for (int dx = 0; dx < 3; ++dx) {
            const int x = ox * 2 + dx - 1;
            if (x < 0 || x >= Win) continue;
            const float* ip = in + (size_t)(b * Win * Win + y * Win + x) * 128;
            const float* wp = wt + (dy * 3 + dx) * 128 + oc;
            for (int ic = 0; ic < 128; ++ic)
                acc += ip[ic] * wp[ic * 1152];
        }
    }
    out[(size_t)(b * Wout * Wout + pos) * 128 + oc] = fmaxf(acc, 0.f);
}

// ---------------- NMS: 1 block per batch ----------------
__global__ __launch_bounds__(256)
void nms(const float* __restrict__ scores, const int* __restrict__ anchors,
         int* __restrict__ top_idx)
{
    __shared__ float sc[1614];
    __shared__ unsigned char valid[1614];
    __shared__ float rv[256];
    __shared__ int ri[256];
    const int b = blockIdx.x, tid = threadIdx.x;
    for (int i = tid; i < 1614; i += 256) { sc[i] = scores[b * 1614 + i]; valid[i] = 1; }
    __syncthreads();
    for (int r = 0; r < 4; ++r) {
        float bv = -INFINITY; int bi = 0x7fffffff;
        for (int i = tid; i < 1614; i += 256) {
            const float v = valid[i] ? sc[i] : -INFINITY;
            if (v > bv || (v == bv && i < bi)) { bv = v; bi = i; }
        }
        rv[tid] = bv; ri[tid] = bi;
        __syncthreads();
        for (int s = 128; s > 0; s >>= 1) {
            if (tid < s) {
                const float v2 = rv[tid + s]; const int i2 = ri[tid + s];
                if (v2 > rv[tid] || (v2 == rv[tid] && i2 < ri[tid])) { rv[tid] = v2; ri[tid] = i2; }
            }
            __syncthreads();
        }
        const int pick = ri[0];
        if (tid == 0) top_idx[b * 4 + r] = pick;
        const float py0 = (float)anchors[pick * 4 + 0], px0 = (float)anchors[pick * 4 + 1];
        const float py1 = (float)anchors[pick * 4 + 2], px1 = (float)anchors[pick * 4 + 3];
        const float pa = (py1 - py0) * (px1 - px0);
        for (int i = tid; i < 1614; i += 256) {
            const float y0 = (float)anchors[i * 4 + 0], x0 = (float)anchors[i * 4 + 1];
            const float y1 = (float)anchors[i * 4 + 2], x1 = (float)anchors[i * 4 + 3];
            const float ih = fminf(y1, py1) - fmaxf(y0, py0);
            const float iw = fminf(x1, px1) - fmaxf(x0, px0);
            const float inter = (ih < 0.f || iw < 0.f) ? 0.f : ih * iw;
            const float area = (y1 - y0) * (x1 - x0);
            const float iou = inter / ((area + pa) - inter);
            if (iou >= 0.25f) valid[i] = 0;
        }
        __syncthreads();
    }
}

// ---------------- bilinear crop-resize from implicitly padded x ----------------
__global__ __launch_bounds__(256)
void crop_resize(const float* __restrict__ x, const int* __restrict__ anchors,
                 const int* __restrict__ top_idx, float* __restrict__ part)
{
    const int t = blockIdx.x * 256 + threadIdx.x;
    if (t >= 64 * 3 * 224 * 224) return;
    const int txp = t % 224;
    const int typ = (t / 224) % 224;
    const int c = (t / (224 * 224)) % 3;
    const int q = t / (3 * 224 * 224);
    const int idx = top_idx[q];
    const int y0 = anchors[idx * 4 + 0], x0 = anchors[idx * 4 + 1];
    const int y1 = anchors[idx * 4 + 2], x1 = anchors[idx * 4 + 3];
    const float h = (float)(y1 - y0), w = (float)(x1 - x0);
    const float sy = (float)typ * (h - 1.0f) / 223.0f;
    const float sx = (float)txp * (w - 1.0f) / 223.0f;
    const float fy = floorf(sy), fx = floorf(sx);
    const float wy = sy - fy, wx = sx - fx;
    const int iy0 = y0 + (int)fy, ix0 = x0 + (int)fx;
    const int iy1 = min(iy0 + 1, y1 - 1), ix1 = min(ix0 + 1, x1 - 1);
    const float* xb = x + (size_t)((q >> 2) * 3 + c) * 448 * 448;
    auto sample = [&](int yy, int xx) -> float {
        yy -= 224; xx -= 224;
        return (yy >= 0 && yy < 448 && xx >= 0 && xx < 448) ? xb[yy * 448 + xx] : 0.f;
    };
    const float v00 = sample(iy0, ix0), v01 = sample(iy0, ix1);
    const float v10 = sample(iy1, ix0), v11 = sample(iy1, ix1);
    const float top = v00 * (1.f - wx) + v01 * wx;
    const float bot = v10 * (1.f - wx) + v11 * wx;
    part[t] = top * (1.f - wy) + bot * wy;
}

// ---------------- means into concat ----------------
__global__ __launch_bounds__(256)
void part_mean(const float* __restrict__ pconv, float* __restrict__ concat)
{
    const int t = blockIdx.x * 256 + threadIdx.x;
    if (t >= 64 * 2048) return;
    const int n = t & 2047, q = t >> 11;
    float s = 0.f;
    for (int p = 0; p < 49; ++p) s += pconv[(size_t)(q * 49 + p) * 2048 + n];
    const int b = q >> 2, tt = q & 3;
    concat[(size_t)b * 10240 + tt * 2048 + n] = s / 49.f;
}

__global__ __launch_bounds__(256)
void raw_mean(const float* __restrict__ raw, float* __restrict__ concat)
{
    const int t = blockIdx.x * 256 + threadIdx.x;
    if (t >= 16 * 2048) return;
    const int n = t & 2047, b = t >> 11;
    float s = 0.f;
    for (int p = 0; p < 196; ++p) s += raw[(size_t)(b * 196 + p) * 2048 + n];
    concat[(size_t)b * 10240 + 8192 + n] = s / 196.f;
}

// ---------------- classifier (wave per (b,cls)) ----------------
__global__ __launch_bounds__(256)
void classifier(const float* __restrict__ concat, const float* __restrict__ w,
                const float* __restrict__ bias, float* __restrict__ out)
{
    const int wid = (blockIdx.x * 256 + threadIdx.x) >> 6;
    const int lane = threadIdx.x & 63;
    if (wid >= 3200) return;
    const int cls = wid % 200, b = wid / 200;
    const float* cr = concat + (size_t)b * 10240;
    const float* wr = w + (size_t)cls * 10240;
    float acc = 0.f;
    for (int k = lane; k < 10240; k += 64) acc += cr[k] * wr[k];
    #pragma unroll
    for (int s = 32; s > 0; s >>= 1) acc += __shfl_down(acc, s, 64);
    if (lane == 0) out[b * 200 + cls] = acc + bias[cls];
}

extern "C" void kernel_launch(void* const* d_in, const int* in_sizes, int n_in,
                              void* d_out, int out_size, void* d_ws, size_t ws_size,
                              hipStream_t stream)
{
    const float* x     = (const float*)d_in[0];
    const float* bb_w  = (const float*)d_in[1];
    const float* bb_b  = (const float*)d_in[2];
    const float* n1_dw = (const float*)d_in[3];
    const float* n1_db = (const float*)d_in[4];
    const float* n1_tw = (const float*)d_in[5];
    const float* n1_tb = (const float*)d_in[6];
    const float* n2_dw = (const float*)d_in[7];
    const float* n2_db = (const float*)d_in[8];
    const float* n2_tw = (const float*)d_in[9];
    const float* n2_tb = (const float*)d_in[10];
    const float* n3_dw = (const float*)d_in[11];
    const float* n3_db = (const float*)d_in[12];
    const float* n3_tw = (const float*)d_in[13];
    const float* n3_tb = (const float*)d_in[14];
    const float* cn_w  = (const float*)d_in[15];
    const float* cn_b  = (const float*)d_in[16];
    const int*   anchors = (const int*)d_in[17];
    float* out = (float*)d_out;
    float* ws  = (float*)d_ws;

    float* raw    = ws + WS_RAW;
    float* y1p    = ws + WS_Y1P;
    float* y1     = ws + WS_Y1;
    float* y2     = ws + WS_Y2;
    float* y3     = ws + WS_Y3;
    float* scores = ws + WS_SCORES;
    float* wt2    = ws + WS_WT2;
    float* wt3    = ws + WS_WT3;
    float* concat = ws + WS_CONCAT;
    int*   topidx = (int*)(ws + WS_TOPIDX);
    float* part   = ws + WS_PART;
    float* pconv  = ws + WS_PCONV;

    wtrans<<<576, 256, 0, stream>>>(n2_dw, wt2);
    wtrans<<<576, 256, 0, stream>>>(n3_dw, wt3);

    patch_gemm<0><<<dim3(25, 16), 256, 0, stream>>>(x, bb_w, bb_b, raw);
    nav1_gemm<<<dim3(25, 16), 256, 0, stream>>>(raw, n1_dw, y1p);
    y1_reduce<<<1568, 256, 0, stream>>>(y1p, n1_db, y1);

    tidy<<<4704, 256, 0, stream>>>(y1, n1_tw, n1_tb, scores, 196, 6, 0);
    conv_s2<<<392, 256, 0, stream>>>(y1, wt2, n2_db, y2, 14, 7);
    tidy<<<1176, 256, 0, stream>>>(y2, n2_tw, n2_tb, scores, 49, 6, 1176);
    conv_s2<<<128, 256, 0, stream>>>(y2, wt3, n3_db, y3, 7, 4);
    tidy<<<576, 256, 0, stream>>>(y3, n3_tw, n3_tb, scores, 16, 9, 1470);

    nms<<<16, 256, 0, stream>>>(scores, anchors, topidx);
    crop_resize<<<37632, 256, 0, stream>>>(x, anchors, topidx, part);

    patch_gemm<1><<<dim3(25, 16), 256, 0, stream>>>(part, bb_w, bb_b, pconv);
    part_mean<<<512, 256, 0, stream>>>(pconv, concat);
    raw_mean<<<128, 256, 0, stream>>>(raw, concat);
    classifier<<<800, 256, 0, stream>>>(concat, cn_w, cn_b, out);
}

// Round 2
// 789.564 us; speedup vs baseline: 2.3380x; 2.3380x over previous
//
#include <hip/hip_runtime.h>
#include <cstdint>
#include <math.h>

typedef __attribute__((ext_vector_type(8))) short short8;
typedef __attribute__((ext_vector_type(4))) float floatx4;

// ---------------- workspace layout (float offsets) ----------------
#define WS_RAW     0ull                 // 3136*2048
#define WS_Y1P     6422528ull           // 9*3136*128   (aliased by pconv later)
#define WS_Y1      10035200ull          // 3136*128
#define WS_WT1     10436608ull          // 128*18432
#define WS_Y2      12795904ull          // 784*128
#define WS_Y3      12896256ull          // 256*128
#define WS_SCORES  12929024ull          // 16*1614
#define WS_WT2     12954848ull          // 147456
#define WS_WT3     13102304ull          // 147456
#define WS_CONCAT  13249760ull          // 16*10240
#define WS_TOPIDX  13413600ull          // 64 ints
#define WS_PART    13413664ull          // 64*3*224*224
#define WS_PCONV   WS_Y1P               // 3136*2048 alias over [y1p,y1,wt1,y2-head] (all dead)

__device__ __forceinline__ unsigned short f2bf(float f) {
    unsigned int u = __float_as_uint(f);
    return (unsigned short)((u + 0x7fffu + ((u >> 16) & 1u)) >> 16);
}
__device__ __forceinline__ float bf2f(unsigned short h) {
    return __uint_as_float(((unsigned int)h) << 16);
}

// =============== unified split-bf16 MFMA GEMM ===============
// C[m][n] = sum_k A[m][k]*B[n][k]  (+bias for ASRC 0/1)
// ASRC 0: A = 32x32 patches of x (16,3,448,448), M=3136, N=2048, K=3072, out raw[m][2048]
// ASRC 1: A = 32x32 patches of part (64,3,224,224), same shape, out pconv[m][2048]
// ASRC 2: A = raw[3136][2048] with 3x3 halo (tap = blockIdx.x), B = wt1, K=2048/tap,
//         out y1p[tap][3136][128]
// PREC 3: split hi/lo, 3 MFMAs (fp32-equivalent). PREC 1: plain bf16.
template<int ASRC, int PREC>
__global__ __launch_bounds__(256)
void mgemm(const float* __restrict__ Asrc, const float* __restrict__ Bsrc,
           const float* __restrict__ bias, float* __restrict__ outp)
{
    constexpr int KSTEPS = (ASRC == 2) ? 64 : 96;
    constexpr int LDA = 40;   // bf16 elems per row (32 + pad to keep 16B align, ~2-way banks)
    __shared__ unsigned short Ahi[128 * LDA];
    __shared__ unsigned short Bhi[128 * LDA];
    __shared__ unsigned short Alo[PREC == 3 ? 128 * LDA : 1];
    __shared__ unsigned short Blo[PREC == 3 ? 128 * LDA : 1];

    const int tid = threadIdx.x;
    const int nt2 = blockIdx.x;   // n-tile (ASRC 0/1) or tap (ASRC 2)
    const int mt  = blockIdx.y;

    // ---- staging geometry (thread covers 16 consecutive k of one A row + one B row)
    const int row = tid >> 1;
    const int ko  = (tid & 1) * 16;
    const int am  = mt * 128 + row;
    bool avalid;
    size_t abase = 0;
    if constexpr (ASRC == 0) {
        const int ab = am / 196, apos = am % 196, aoy = apos / 14, aox = apos % 14;
        avalid = am < 3136;
        abase = ((size_t)(ab * 3) * 448 + (size_t)aoy * 32) * 448 + aox * 32 + ko;
    } else if constexpr (ASRC == 1) {
        const int ab = am / 49, apos = am % 49, aoy = apos / 7, aox = apos % 7;
        avalid = am < 3136;
        abase = ((size_t)(ab * 3) * 224 + (size_t)aoy * 32) * 224 + aox * 32 + ko;
    } else {
        const int ab = am / 196, apos = am % 196, aoy = apos / 14, aox = apos % 14;
        const int dy = nt2 / 3, dx = nt2 % 3;
        const int iy = aoy + dy - 1, ix = aox + dx - 1;
        avalid = (am < 3136) && iy >= 0 && iy < 14 && ix >= 0 && ix < 14;
        abase = avalid ? ((size_t)(ab * 196 + iy * 14 + ix)) * 2048 + ko : 0;
    }
    size_t bbase;
    if constexpr (ASRC == 2) bbase = (size_t)row * 18432 + (size_t)nt2 * 2048 + ko;
    else                     bbase = (size_t)(nt2 * 128 + row) * 3072 + ko;

    // ---- compute geometry (4 waves, each 64x64 of the 128x128 tile)
    const int lane = tid & 63, wv = tid >> 6;
    const int wm = wv >> 1, wn = wv & 1;
    const int lm = lane & 15, quad = lane >> 4;
    int afo[4], bfo[4];
    #pragma unroll
    for (int i = 0; i < 4; ++i) afo[i] = (wm * 64 + i * 16 + lm) * LDA + quad * 8;
    #pragma unroll
    for (int j = 0; j < 4; ++j) bfo[j] = (wn * 64 + j * 16 + lm) * LDA + quad * 8;

    floatx4 acc[4][4];
    const floatx4 fz = {0.f, 0.f, 0.f, 0.f};
    #pragma unroll
    for (int i = 0; i < 4; ++i)
        #pragma unroll
        for (int j = 0; j < 4; ++j) acc[i][j] = fz;

    for (int s = 0; s < KSTEPS; ++s) {
        // ---- stage + split
        float va[16], vb[16];
        size_t aoff;
        if constexpr (ASRC == 0)      aoff = (size_t)(((s >> 5) * 448 + (s & 31))) * 448;
        else if constexpr (ASRC == 1) aoff = (size_t)(((s >> 5) * 224 + (s & 31))) * 224;
        else                          aoff = (size_t)s * 32;
        if (avalid) {
            const float* p = Asrc + abase + aoff;
            *(float4*)&va[0]  = *(const float4*)(p);
            *(float4*)&va[4]  = *(const float4*)(p + 4);
            *(float4*)&va[8]  = *(const float4*)(p + 8);
            *(float4*)&va[12] = *(const float4*)(p + 12);
        } else {
            #pragma unroll
            for (int j = 0; j < 16; ++j) va[j] = 0.f;
        }
        {
            const float* p = Bsrc + bbase + (size_t)s * 32;
            *(float4*)&vb[0]  = *(const float4*)(p);
            *(float4*)&vb[4]  = *(const float4*)(p + 4);
            *(float4*)&vb[8]  = *(const float4*)(p + 8);
            *(float4*)&vb[12] = *(const float4*)(p + 12);
        }
        #pragma unroll
        for (int g = 0; g < 2; ++g) {
            short8 ha, hb;
            #pragma unroll
            for (int j = 0; j < 8; ++j) {
                ha[j] = (short)f2bf(va[g * 8 + j]);
                hb[j] = (short)f2bf(vb[g * 8 + j]);
            }
            *(short8*)&Ahi[row * LDA + ko + g * 8] = ha;
            *(short8*)&Bhi[row * LDA + ko + g * 8] = hb;
            if constexpr (PREC == 3) {
                short8 la, lb;
                #pragma unroll
                for (int j = 0; j < 8; ++j) {
                    la[j] = (short)f2bf(va[g * 8 + j] - bf2f((unsigned short)ha[j]));
                    lb[j] = (short)f2bf(vb[g * 8 + j] - bf2f((unsigned short)hb[j]));
                }
                *(short8*)&Alo[row * LDA + ko + g * 8] = la;
                *(short8*)&Blo[row * LDA + ko + g * 8] = lb;
            }
        }
        __syncthreads();

        // ---- MFMA
        short8 ah[4], bh[4];
        #pragma unroll
        for (int i = 0; i < 4; ++i) ah[i] = *(const short8*)&Ahi[afo[i]];
        #pragma unroll
        for (int j = 0; j < 4; ++j) bh[j] = *(const short8*)&Bhi[bfo[j]];
        if constexpr (PREC == 3) {
            short8 al[4], bl[4];
            #pragma unroll
            for (int i = 0; i < 4; ++i) al[i] = *(const short8*)&Alo[afo[i]];
            #pragma unroll
            for (int j = 0; j < 4; ++j) bl[j] = *(const short8*)&Blo[bfo[j]];
            #pragma unroll
            for (int i = 0; i < 4; ++i)
                #pragma unroll
                for (int j = 0; j < 4; ++j) {
                    acc[i][j] = __builtin_amdgcn_mfma_f32_16x16x32_bf16(ah[i], bh[j], acc[i][j], 0, 0, 0);
                    acc[i][j] = __builtin_amdgcn_mfma_f32_16x16x32_bf16(ah[i], bl[j], acc[i][j], 0, 0, 0);
                    acc[i][j] = __builtin_amdgcn_mfma_f32_16x16x32_bf16(al[i], bh[j], acc[i][j], 0, 0, 0);
                }
        } else {
            #pragma unroll
            for (int i = 0; i < 4; ++i)
                #pragma unroll
                for (int j = 0; j < 4; ++j)
                    acc[i][j] = __builtin_amdgcn_mfma_f32_16x16x32_bf16(ah[i], bh[j], acc[i][j], 0, 0, 0);
        }
        __syncthreads();
    }

    // ---- epilogue: D col = lane&15 (n), row = quad*4 + r (m)
    #pragma unroll
    for (int i = 0; i < 4; ++i) {
        const int mbase = mt * 128 + wm * 64 + i * 16 + quad * 4;
        #pragma unroll
        for (int j = 0; j < 4; ++j) {
            const int n0 = wn * 64 + j * 16 + lm;
            #pragma unroll
            for (int r = 0; r < 4; ++r) {
                const int m = mbase + r;
                if (m < 3136) {
                    if constexpr (ASRC == 2) {
                        outp[((size_t)nt2 * 3136 + m) * 128 + n0] = acc[i][j][r];
                    } else {
                        const int ng = nt2 * 128 + n0;
                        outp[(size_t)m * 2048 + ng] = acc[i][j][r] + bias[ng];
                    }
                }
            }
        }
    }
}

// ---- nav1 weight transpose: wt1[o][tap][ic] = n1_dw[o][ic][tap]
__global__ __launch_bounds__(256)
void wtrans1(const float* __restrict__ w, float* __restrict__ wt)
{
    const int t = blockIdx.x * 256 + threadIdx.x;
    if (t >= 128 * 18432) return;
    const int o = t / 18432, r = t % 18432;
    const int tap = r >> 11, ic = r & 2047;
    wt[t] = w[o * 18432 + ic * 9 + tap];
}

__global__ __launch_bounds__(256)
void y1_reduce(const float* __restrict__ y1p, const float* __restrict__ bias,
               float* __restrict__ y1)
{
    const int t = blockIdx.x * 256 + threadIdx.x;
    if (t >= 3136 * 128) return;
    const int n = t & 127;
    float s = bias[n];
    #pragma unroll
    for (int ks = 0; ks < 9; ++ks) s += y1p[(size_t)ks * 3136 * 128 + t];
    y1[t] = fmaxf(s, 0.f);
}

// ---------------- 1x1 "tidy" convs -> scores (wave per output) ----------------
__global__ __launch_bounds__(256)
void tidy(const float* __restrict__ in, const float* __restrict__ w,
          const float* __restrict__ bias, float* __restrict__ scores,
          int P, int nch, int off)
{
    const int wid = (blockIdx.x * 256 + threadIdx.x) >> 6;
    const int lane = threadIdx.x & 63;
    const int total = 16 * nch * P;
    if (wid >= total) return;
    const int pos = wid % P, ch = (wid / P) % nch, b = wid / (P * nch);
    const float* r = in + (size_t)(b * P + pos) * 128;
    const float* wr = w + ch * 128;
    float acc = r[lane] * wr[lane] + r[lane + 64] * wr[lane + 64];
    #pragma unroll
    for (int s = 32; s > 0; s >>= 1) acc += __shfl_down(acc, s, 64);
    if (lane == 0) scores[b * 1614 + off + ch * P + pos] = acc + bias[ch];
}

// ---------------- weight transpose for strided convs ----------------
__global__ __launch_bounds__(256)
void wtrans(const float* __restrict__ w, float* __restrict__ wt)
{
    const int t = blockIdx.x * 256 + threadIdx.x;
    if (t >= 147456) return;
    const int oc = t / 1152, r = t % 1152;
    wt[r * 128 + oc] = w[t];
}

// ---------------- 3x3 stride-2 conv, 128->128, relu ----------------
__global__ __launch_bounds__(256)
void conv_s2(const float* __restrict__ in, const float* __restrict__ wt,
             const float* __restrict__ bias, float* __restrict__ out,
             int Win, int Wout)
{
    const int t = blockIdx.x * 256 + threadIdx.x;
    const int oc = t & 127;
    const int pos = (t >> 7) % (Wout * Wout);
    const int b = t / (128 * Wout * Wout);
    if (b >= 16) return;
    const int oy = pos / Wout, ox = pos % Wout;
    float acc = bias[oc];
    for (int dy = 0; dy < 3; ++dy) {
        const int y = oy * 2 + dy - 1;
        if (y < 0 || y >= Win) continue;
        for (int dx = 0; dx < 3; ++dx) {
            const int x = ox * 2 + dx - 1;
            if (x < 0 || x >= Win) continue;
            const float* ip = in + (size_t)(b * Win * Win + y * Win + x) * 128;
            const float* wp = wt + (dy * 3 + dx) * 128 + oc;
            for (int ic = 0; ic < 128; ++ic)
                acc += ip[ic] * wp[ic * 1152];
        }
    }
    out[(size_t)(b * Wout * Wout + pos) * 128 + oc] = fmaxf(acc, 0.f);
}

// ---------------- NMS: 1 block per batch ----------------
__global__ __launch_bounds__(256)
void nms(const float* __restrict__ scores, const int* __restrict__ anchors,
         int* __restrict__ top_idx)
{
    __shared__ float sc[1614];
    __shared__ unsigned char valid[1614];
    __shared__ float rv[256];
    __shared__ int ri[256];
    const int b = blockIdx.x, tid = threadIdx.x;
    for (int i = tid; i < 1614; i += 256) { sc[i] = scores[b * 1614 + i]; valid[i] = 1; }
    __syncthreads();
    for (int r = 0; r < 4; ++r) {
        float bv = -INFINITY; int bi = 0x7fffffff;
        for (int i = tid; i < 1614; i += 256) {
            const float v = valid[i] ? sc[i] : -INFINITY;
            if (v > bv || (v == bv && i < bi)) { bv = v; bi = i; }
        }
        rv[tid] = bv; ri[tid] = bi;
        __syncthreads();
        for (int s = 128; s > 0; s >>= 1) {
            if (tid < s) {
                const float v2 = rv[tid + s]; const int i2 = ri[tid + s];
                if (v2 > rv[tid] || (v2 == rv[tid] && i2 < ri[tid])) { rv[tid] = v2; ri[tid] = i2; }
            }
            __syncthreads();
        }
        const int pick = ri[0];
        if (tid == 0) top_idx[b * 4 + r] = pick;
        const float py0 = (float)anchors[pick * 4 + 0], px0 = (float)anchors[pick * 4 + 1];
        const float py1 = (float)anchors[pick * 4 + 2], px1 = (float)anchors[pick * 4 + 3];
        const float pa = (py1 - py0) * (px1 - px0);
        for (int i = tid; i < 1614; i += 256) {
            const float y0 = (float)anchors[i * 4 + 0], x0 = (float)anchors[i * 4 + 1];
            const float y1 = (float)anchors[i * 4 + 2], x1 = (float)anchors[i * 4 + 3];
            const float ih = fminf(y1, py1) - fmaxf(y0, py0);
            const float iw = fminf(x1, px1) - fmaxf(x0, px0);
            const float inter = (ih < 0.f || iw < 0.f) ? 0.f : ih * iw;
            const float area = (y1 - y0) * (x1 - x0);
            const float iou = inter / ((area + pa) - inter);
            if (iou >= 0.25f) valid[i] = 0;
        }
        __syncthreads();
    }
}

// ---------------- bilinear crop-resize from implicitly padded x ----------------
__global__ __launch_bounds__(256)
void crop_resize(const float* __restrict__ x, const int* __restrict__ anchors,
                 const int* __restrict__ top_idx, float* __restrict__ part)
{
    const int t = blockIdx.x * 256 + threadIdx.x;
    if (t >= 64 * 3 * 224 * 224) return;
    const int txp = t % 224;
    const int typ = (t / 224) % 224;
    const int c = (t / (224 * 224)) % 3;
    const int q = t / (3 * 224 * 224);
    const int idx = top_idx[q];
    const int y0 = anchors[idx * 4 + 0], x0 = anchors[idx * 4 + 1];
    const int y1 = anchors[idx * 4 + 2], x1 = anchors[idx * 4 + 3];
    const float h = (float)(y1 - y0), w = (float)(x1 - x0);
    const float sy = (float)typ * (h - 1.0f) / 223.0f;
    const float sx = (float)txp * (w - 1.0f) / 223.0f;
    const float fy = floorf(sy), fx = floorf(sx);
    const float wy = sy - fy, wx = sx - fx;
    const int iy0 = y0 + (int)fy, ix0 = x0 + (int)fx;
    const int iy1 = min(iy0 + 1, y1 - 1), ix1 = min(ix0 + 1, x1 - 1);
    const float* xb = x + (size_t)((q >> 2) * 3 + c) * 448 * 448;
    auto sample = [&](int yy, int xx) -> float {
        yy -= 224; xx -= 224;
        return (yy >= 0 && yy < 448 && xx >= 0 && xx < 448) ? xb[yy * 448 + xx] : 0.f;
    };
    const float v00 = sample(iy0, ix0), v01 = sample(iy0, ix1);
    const float v10 = sample(iy1, ix0), v11 = sample(iy1, ix1);
    const float top = v00 * (1.f - wx) + v01 * wx;
    const float bot = v10 * (1.f - wx) + v11 * wx;
    part[t] = top * (1.f - wy) + bot * wy;
}

// ---------------- means into concat ----------------
__global__ __launch_bounds__(256)
void part_mean(const float* __restrict__ pconv, float* __restrict__ concat)
{
    const int t = blockIdx.x * 256 + threadIdx.x;
    if (t >= 64 * 2048) return;
    const int n = t & 2047, q = t >> 11;
    float s = 0.f;
    for (int p = 0; p < 49; ++p) s += pconv[(size_t)(q * 49 + p) * 2048 + n];
    const int b = q >> 2, tt = q & 3;
    concat[(size_t)b * 10240 + tt * 2048 + n] = s / 49.f;
}

__global__ __launch_bounds__(256)
void raw_mean(const float* __restrict__ raw, float* __restrict__ concat)
{
    const int t = blockIdx.x * 256 + threadIdx.x;
    if (t >= 16 * 2048) return;
    const int n = t & 2047, b = t >> 11;
    float s = 0.f;
    for (int p = 0; p < 196; ++p) s += raw[(size_t)(b * 196 + p) * 2048 + n];
    concat[(size_t)b * 10240 + 8192 + n] = s / 196.f;
}

// ---------------- classifier (wave per (b,cls)) ----------------
__global__ __launch_bounds__(256)
void classifier(const float* __restrict__ concat, const float* __restrict__ w,
                const float* __restrict__ bias, float* __restrict__ out)
{
    const int wid = (blockIdx.x * 256 + threadIdx.x) >> 6;
    const int lane = threadIdx.x & 63;
    if (wid >= 3200) return;
    const int cls = wid % 200, b = wid / 200;
    const float* cr = concat + (size_t)b * 10240;
    const float* wr = w + (size_t)cls * 10240;
    float acc = 0.f;
    for (int k = lane; k < 10240; k += 64) acc += cr[k] * wr[k];
    #pragma unroll
    for (int s = 32; s > 0; s >>= 1) acc += __shfl_down(acc, s, 64);
    if (lane == 0) out[b * 200 + cls] = acc + bias[cls];
}

extern "C" void kernel_launch(void* const* d_in, const int* in_sizes, int n_in,
                              void* d_out, int out_size, void* d_ws, size_t ws_size,
                              hipStream_t stream)
{
    const float* x     = (const float*)d_in[0];
    const float* bb_w  = (const float*)d_in[1];
    const float* bb_b  = (const float*)d_in[2];
    const float* n1_dw = (const float*)d_in[3];
    const float* n1_db = (const float*)d_in[4];
    const float* n1_tw = (const float*)d_in[5];
    const float* n1_tb = (const float*)d_in[6];
    const float* n2_dw = (const float*)d_in[7];
    const float* n2_db = (const float*)d_in[8];
    const float* n2_tw = (const float*)d_in[9];
    const float* n2_tb = (const float*)d_in[10];
    const float* n3_dw = (const float*)d_in[11];
    const float* n3_db = (const float*)d_in[12];
    const float* n3_tw = (const float*)d_in[13];
    const float* n3_tb = (const float*)d_in[14];
    const float* cn_w  = (const float*)d_in[15];
    const float* cn_b  = (const float*)d_in[16];
    const int*   anchors = (const int*)d_in[17];
    float* out = (float*)d_out;
    float* ws  = (float*)d_ws;

    float* raw    = ws + WS_RAW;
    float* y1p    = ws + WS_Y1P;
    float* y1     = ws + WS_Y1;
    float* wt1    = ws + WS_WT1;
    float* y2     = ws + WS_Y2;
    float* y3     = ws + WS_Y3;
    float* scores = ws + WS_SCORES;
    float* wt2    = ws + WS_WT2;
    float* wt3    = ws + WS_WT3;
    float* concat = ws + WS_CONCAT;
    int*   topidx = (int*)(ws + WS_TOPIDX);
    float* part   = ws + WS_PART;
    float* pconv  = ws + WS_PCONV;

    wtrans1<<<9216, 256, 0, stream>>>(n1_dw, wt1);
    wtrans<<<576, 256, 0, stream>>>(n2_dw, wt2);
    wtrans<<<576, 256, 0, stream>>>(n3_dw, wt3);

    // raw = patchify(x) @ bb_w, split-bf16 (score path: fp32-equivalent)
    mgemm<0, 3><<<dim3(16, 25), 256, 0, stream>>>(x, bb_w, bb_b, raw);
    // nav1: 9 taps K-split
    mgemm<2, 3><<<dim3(9, 25), 256, 0, stream>>>(raw, wt1, nullptr, y1p);
    y1_reduce<<<1568, 256, 0, stream>>>(y1p, n1_db, y1);

    tidy<<<4704, 256, 0, stream>>>(y1, n1_tw, n1_tb, scores, 196, 6, 0);
    conv_s2<<<392, 256, 0, stream>>>(y1, wt2, n2_db, y2, 14, 7);
    tidy<<<1176, 256, 0, stream>>>(y2, n2_tw, n2_tb, scores, 49, 6, 1176);
    conv_s2<<<128, 256, 0, stream>>>(y2, wt3, n3_db, y3, 7, 4);
    tidy<<<576, 256, 0, stream>>>(y3, n3_tw, n3_tb, scores, 16, 9, 1470);

    nms<<<16, 256, 0, stream>>>(scores, anchors, topidx);
    crop_resize<<<37632, 256, 0, stream>>>(x, anchors, topidx, part);

    // part features: plain bf16 (logit path only)
    mgemm<1, 1><<<dim3(16, 25), 256, 0, stream>>>(part, bb_w, bb_b, pconv);
    part_mean<<<512, 256, 0, stream>>>(pconv, concat);
    raw_mean<<<128, 256, 0, stream>>>(raw, concat);
    classifier<<<800, 256, 0, stream>>>(concat, cn_w, cn_b, out);
}

// Round 4
// 654.675 us; speedup vs baseline: 2.8197x; 1.2060x over previous
//
#include <hip/hip_runtime.h>
#include <cstdint>
#include <math.h>

typedef unsigned short ushort_t;
typedef __attribute__((ext_vector_type(8))) short short8;
typedef __attribute__((ext_vector_type(4))) float floatx4;

// ---------------- workspace byte layout ----------------
// 0         bbwsw_hi 12,582,912   [32 nt][96 s][4 kg][64 n][16B]
// 12582912  bbwsw_lo 12,582,912
// 25165824  zpad     1,024
// 25166848  topidx   1,024
// 25167872  scores   103,424 (16*1614*4)
// 25271296  y1       1,605,632
// 26876928  y2       401,408
// 27278336  y3       131,072
// 27409408  concat   655,360
// 28064768  E region 39,321,600:
//    phase1: xsw_hi 19,660,800 @E+0 ; xsw_lo @E+19,660,800     [25 mt][96][4][128][16B]
//    phase2: y1p 14,450,688 @E+0 ; wt1sw_hi @E+14,450,688 (4,718,592) ;
//            wt1sw_lo @E+19,169,280 ; wt2t @E+23,887,872 (589,824) ; wt3t @E+24,477,696
//    phase3: pconv 25,690,112 @E+0
// 67386368  F region 25,690,112:
//    phase1: raw_hi 12,845,056 @F+0 ; raw_lo @F+12,845,056     row-major [3136][2048] bf16
//    phase2: partsw_hi 19,660,800 @F+0                          [25 mt][96][4][128][16B]
//    NOTE: raw_mean MUST run before crop_resize (psw clobbers rawh/rawl).
// total 93,076,480

__device__ __forceinline__ ushort_t f2bf(float f) {
    unsigned int u = __float_as_uint(f);
    return (ushort_t)((u + 0x7fffu + ((u >> 16) & 1u)) >> 16);
}
__device__ __forceinline__ float bf2f(ushort_t h) {
    return __uint_as_float(((unsigned int)h) << 16);
}

typedef __attribute__((address_space(3))) unsigned int lds_u32;
typedef const __attribute__((address_space(1))) unsigned int glb_u32;
__device__ __forceinline__ void glds16(const void* g, void* l) {
    __builtin_amdgcn_global_load_lds((glb_u32*)g, (lds_u32*)l, 16, 0, 0);
}

// ================= prep1: bb_w -> swizzled bf16 hi/lo, + zero page =================
__global__ __launch_bounds__(256)
void prep1(const float* __restrict__ bbw, ushort_t* __restrict__ bh,
           ushort_t* __restrict__ bl, float* __restrict__ zpad)
{
    const int t = blockIdx.x * 256 + threadIdx.x;   // 786432 total
    if (t < 256) zpad[t] = 0.f;
    if (t >= 2048 * 384) return;
    const int n = t % 2048, k8 = t / 2048;
    const float* p = bbw + (size_t)n * 3072 + k8 * 8;
    float f[8];
    *(float4*)&f[0] = *(const float4*)p;
    *(float4*)&f[4] = *(const float4*)(p + 4);
    const int nt = n >> 6, nr = n & 63, s = k8 >> 2, kg = k8 & 3;
    const size_t dst = (((size_t)(nt * 96 + s) * 4 + kg) * 64 + nr) * 8;
    short8 h, l;
    #pragma unroll
    for (int j = 0; j < 8; ++j) {
        ushort_t hh = f2bf(f[j]);
        h[j] = (short)hh;
        l[j] = (short)f2bf(f[j] - bf2f(hh));
    }
    *(short8*)(bh + dst) = h;
    *(short8*)(bl + dst) = l;
}

// ================= xconv: x -> patchified swizzled bf16 hi/lo =================
__global__ __launch_bounds__(256)
void xconv(const float* __restrict__ x, ushort_t* __restrict__ ah, ushort_t* __restrict__ al)
{
    const int t = blockIdx.x * 256 + threadIdx.x;   // 1228800 total
    if (t >= 3200 * 384) return;
    const int m = t % 3200, k8 = t / 3200;
    const int mt = m >> 7, mr = m & 127, s = k8 >> 2, kg = k8 & 3;
    const size_t dst = (((size_t)(mt * 96 + s) * 4 + kg) * 128 + mr) * 8;
    float f[8];
    if (m < 3136) {
        const int bq = m / 196, pos = m % 196, oy = pos / 14, ox = pos % 14;
        const int k = k8 * 8, c = k >> 10, r = (k >> 5) & 31, cc = k & 31;
        const float* p = x + ((size_t)(bq * 3 + c) * 448 + oy * 32 + r) * 448 + ox * 32 + cc;
        *(float4*)&f[0] = *(const float4*)p;
        *(float4*)&f[4] = *(const float4*)(p + 4);
    } else {
        #pragma unroll
        for (int j = 0; j < 8; ++j) f[j] = 0.f;
    }
    short8 h, l;
    #pragma unroll
    for (int j = 0; j < 8; ++j) {
        ushort_t hh = f2bf(f[j]);
        h[j] = (short)hh;
        l[j] = (short)f2bf(f[j] - bf2f(hh));
    }
    *(short8*)(ah + dst) = h;
    *(short8*)(al + dst) = l;
}

// ================= prep2: wt1 swizzle + wt2/wt3 [tap][ic][oc] =================
__global__ __launch_bounds__(256)
void prep2(const float* __restrict__ n1dw, ushort_t* __restrict__ w1h, ushort_t* __restrict__ w1l,
           const float* __restrict__ n2dw, float* __restrict__ wt2t,
           const float* __restrict__ n3dw, float* __restrict__ wt3t)
{
    const int t = blockIdx.x * 256 + threadIdx.x;   // 589824 total
    if (t < 294912) {
        const int n = t % 128, rest = t / 128;
        const int ic8 = rest % 256, tap = rest / 256;
        const int s = ic8 >> 2, kg = ic8 & 3;
        short8 h, l;
        #pragma unroll
        for (int i = 0; i < 8; ++i) {
            const int ic = ic8 * 8 + i;
            const float v = n1dw[((size_t)n * 2048 + ic) * 9 + tap];
            ushort_t hh = f2bf(v);
            h[i] = (short)hh;
            l[i] = (short)f2bf(v - bf2f(hh));
        }
        const size_t dst = (((size_t)(tap * 64 + s) * 4 + kg) * 128 + n) * 8;
        *(short8*)(w1h + dst) = h;
        *(short8*)(w1l + dst) = l;
    } else if (t < 442368) {
        const int t2 = t - 294912;
        const int oc = t2 % 128, rest = t2 / 128, ic = rest % 128, tap = rest / 128;
        wt2t[(tap * 128 + ic) * 128 + oc] = n2dw[((size_t)oc * 128 + ic) * 9 + tap];
    } else if (t < 589824) {
        const int t2 = t - 442368;
        const int oc = t2 % 128, rest = t2 / 128, ic = rest % 128, tap = rest / 128;
        wt3t[(tap * 128 + ic) * 128 + oc] = n3dw[((size_t)oc * 128 + ic) * 9 + tap];
    }
}

// ================= gemm_x: split-bf16 128Mx64N, K=3072, out raw hi/lo + bias =================
__global__ __launch_bounds__(256)
void gemm_x(const ushort_t* __restrict__ Ah, const ushort_t* __restrict__ Al,
            const ushort_t* __restrict__ Bh, const ushort_t* __restrict__ Bl,
            const float* __restrict__ bias,
            ushort_t* __restrict__ outh, ushort_t* __restrict__ outl)
{
    __shared__ __align__(16) char L[24576]; // Ahi 0, Alo 8192, Bhi 16384, Blo 20480
    const int tid = threadIdx.x, lane = tid & 63, wv = tid >> 6;
    const int nt = blockIdx.x, mt = blockIdx.y;
    const int lm = lane & 15, quad = lane >> 4;
    const int wm = wv >> 1, wn = wv & 1;

    const char* gAh = (const char*)Ah + (size_t)mt * 96 * 8192 + lane * 16;
    const char* gAl = (const char*)Al + (size_t)mt * 96 * 8192 + lane * 16;
    const char* gBh = (const char*)Bh + (size_t)nt * 96 * 4096 + lane * 16;
    const char* gBl = (const char*)Bl + (size_t)nt * 96 * 4096 + lane * 16;

    int afo[4], bfo[2];
    #pragma unroll
    for (int i = 0; i < 4; ++i) afo[i] = (quad * 128 + wm * 64 + i * 16 + lm) * 16;
    #pragma unroll
    for (int j = 0; j < 2; ++j) bfo[j] = (quad * 64 + wn * 32 + j * 16 + lm) * 16;

    floatx4 acc[4][2];
    const floatx4 fz = {0.f, 0.f, 0.f, 0.f};
    #pragma unroll
    for (int i = 0; i < 4; ++i) { acc[i][0] = fz; acc[i][1] = fz; }

    for (int s = 0; s < 96; ++s) {
        const size_t sa = (size_t)s * 8192, sb = (size_t)s * 4096;
        glds16(gAh + sa + (2 * wv) * 1024,     L + 0     + (2 * wv) * 1024);
        glds16(gAh + sa + (2 * wv + 1) * 1024, L + 0     + (2 * wv + 1) * 1024);
        glds16(gAl + sa + (2 * wv) * 1024,     L + 8192  + (2 * wv) * 1024);
        glds16(gAl + sa + (2 * wv + 1) * 1024, L + 8192  + (2 * wv + 1) * 1024);
        glds16(gBh + sb + wv * 1024,           L + 16384 + wv * 1024);
        glds16(gBl + sb + wv * 1024,           L + 20480 + wv * 1024);
        __syncthreads();
        short8 ah[4], al[4], bh[2], bl[2];
        #pragma unroll
        for (int i = 0; i < 4; ++i) { ah[i] = *(const short8*)(L + afo[i]); al[i] = *(const short8*)(L + 8192 + afo[i]); }
        #pragma unroll
        for (int j = 0; j < 2; ++j) { bh[j] = *(const short8*)(L + 16384 + bfo[j]); bl[j] = *(const short8*)(L + 20480 + bfo[j]); }
        #pragma unroll
        for (int i = 0; i < 4; ++i)
            #pragma unroll
            for (int j = 0; j < 2; ++j) {
                acc[i][j] = __builtin_amdgcn_mfma_f32_16x16x32_bf16(ah[i], bh[j], acc[i][j], 0, 0, 0);
                acc[i][j] = __builtin_amdgcn_mfma_f32_16x16x32_bf16(ah[i], bl[j], acc[i][j], 0, 0, 0);
                acc[i][j] = __builtin_amdgcn_mfma_f32_16x16x32_bf16(al[i], bh[j], acc[i][j], 0, 0, 0);
            }
        __syncthreads();
    }
    #pragma unroll
    for (int i = 0; i < 4; ++i) {
        const int m0 = mt * 128 + wm * 64 + i * 16 + quad * 4;
        #pragma unroll
        for (int j = 0; j < 2; ++j) {
            const int n = nt * 64 + wn * 32 + j * 16 + lm;
            const float bv = bias[n];
            #pragma unroll
            for (int r = 0; r < 4; ++r) {
                const int mm = m0 + r;
                if (mm < 3136) {
                    const float v = acc[i][j][r] + bv;
                    const ushort_t h = f2bf(v);
                    outh[(size_t)mm * 2048 + n] = h;
                    outl[(size_t)mm * 2048 + n] = f2bf(v - bf2f(h));
                }
            }
        }
    }
}

// ================= gemm_nav: split-bf16 64Mx128N, K=2048 per tap, out y1p fp32 =================
__global__ __launch_bounds__(256)
void gemm_nav(const ushort_t* __restrict__ rawh, const ushort_t* __restrict__ rawl,
              const ushort_t* __restrict__ Bh, const ushort_t* __restrict__ Bl,
              const char* __restrict__ zpad, float* __restrict__ y1p)
{
    __shared__ __align__(16) char L[24576]; // Ahi 0 (4096), Alo 4096, Bhi 8192 (8192), Blo 16384
    const int tid = threadIdx.x, lane = tid & 63, wv = tid >> 6;
    const int tap = blockIdx.x, mt = blockIdx.y;
    const int lm = lane & 15, quad = lane >> 4;
    const int wm = wv >> 1, wn = wv & 1;

    // per-lane A row (with halo); redirect invalid rows to zero page
    const int grow = mt * 64 + lane;
    const int b = grow / 196, pos = grow % 196, oy = pos / 14, ox = pos % 14;
    const int iy = oy + tap / 3 - 1, ix = ox + tap % 3 - 1;
    const bool av = (iy >= 0 && iy < 14 && ix >= 0 && ix < 14);
    const size_t rowoff = av ? ((size_t)(b * 196 + iy * 14 + ix)) * 4096 : 0;
    const char* aH = av ? (const char*)rawh + rowoff + wv * 16 : zpad;
    const char* aL = av ? (const char*)rawl + rowoff + wv * 16 : zpad;
    const int astep = av ? 64 : 0;
    const char* gBh = (const char*)Bh + (size_t)tap * 64 * 8192 + lane * 16;
    const char* gBl = (const char*)Bl + (size_t)tap * 64 * 8192 + lane * 16;

    int afo[2], bfo[4];
    #pragma unroll
    for (int i = 0; i < 2; ++i) afo[i] = (quad * 64 + wm * 32 + i * 16 + lm) * 16;
    #pragma unroll
    for (int j = 0; j < 4; ++j) bfo[j] = (quad * 128 + wn * 64 + j * 16 + lm) * 16;

    floatx4 acc[2][4];
    const floatx4 fz = {0.f, 0.f, 0.f, 0.f};
    #pragma unroll
    for (int i = 0; i < 2; ++i)
        #pragma unroll
        for (int j = 0; j < 4; ++j) acc[i][j] = fz;

    for (int s = 0; s < 64; ++s) {
        const size_t sb = (size_t)s * 8192;
        glds16(aH + (size_t)s * astep, L + 0    + wv * 1024);
        glds16(aL + (size_t)s * astep, L + 4096 + wv * 1024);
        glds16(gBh + sb + (2 * wv) * 1024,     L + 8192  + (2 * wv) * 1024);
        glds16(gBh + sb + (2 * wv + 1) * 1024, L + 8192  + (2 * wv + 1) * 1024);
        glds16(gBl + sb + (2 * wv) * 1024,     L + 16384 + (2 * wv) * 1024);
        glds16(gBl + sb + (2 * wv + 1) * 1024, L + 16384 + (2 * wv + 1) * 1024);
        __syncthreads();
        short8 ah[2], al[2], bh[4], bl[4];
        #pragma unroll
        for (int i = 0; i < 2; ++i) { ah[i] = *(const short8*)(L + afo[i]); al[i] = *(const short8*)(L + 4096 + afo[i]); }
        #pragma unroll
        for (int j = 0; j < 4; ++j) { bh[j] = *(const short8*)(L + 8192 + bfo[j]); bl[j] = *(const short8*)(L + 16384 + bfo[j]); }
        #pragma unroll
        for (int i = 0; i < 2; ++i)
            #pragma unroll
            for (int j = 0; j < 4; ++j) {
                acc[i][j] = __builtin_amdgcn_mfma_f32_16x16x32_bf16(ah[i], bh[j], acc[i][j], 0, 0, 0);
                acc[i][j] = __builtin_amdgcn_mfma_f32_16x16x32_bf16(ah[i], bl[j], acc[i][j], 0, 0, 0);
                acc[i][j] = __builtin_amdgcn_mfma_f32_16x16x32_bf16(al[i], bh[j], acc[i][j], 0, 0, 0);
            }
        __syncthreads();
    }
    #pragma unroll
    for (int i = 0; i < 2; ++i) {
        const int m0 = mt * 64 + wm * 32 + i * 16 + quad * 4;
        #pragma unroll
        for (int j = 0; j < 4; ++j) {
            const int n = wn * 64 + j * 16 + lm;
            #pragma unroll
            for (int r = 0; r < 4; ++r)
                y1p[((size_t)tap * 3136 + m0 + r) * 128 + n] = acc[i][j][r];
        }
    }
}

// ================= gemm_part: plain bf16 128Mx64N, K=3072, out pconv fp32 + bias =================
__global__ __launch_bounds__(256)
void gemm_part(const ushort_t* __restrict__ Ah, const ushort_t* __restrict__ Bh,
               const float* __restrict__ bias, float* __restrict__ outp)
{
    __shared__ __align__(16) char L[12288]; // Ahi 0 (8192), Bhi 8192 (4096)
    const int tid = threadIdx.x, lane = tid & 63, wv = tid >> 6;
    const int nt = blockIdx.x, mt = blockIdx.y;
    const int lm = lane & 15, quad = lane >> 4;
    const int wm = wv >> 1, wn = wv & 1;

    const char* gAh = (const char*)Ah + (size_t)mt * 96 * 8192 + lane * 16;
    const char* gBh = (const char*)Bh + (size_t)nt * 96 * 4096 + lane * 16;

    int afo[4], bfo[2];
    #pragma unroll
    for (int i = 0; i < 4; ++i) afo[i] = (quad * 128 + wm * 64 + i * 16 + lm) * 16;
    #pragma unroll
    for (int j = 0; j < 2; ++j) bfo[j] = (quad * 64 + wn * 32 + j * 16 + lm) * 16;

    floatx4 acc[4][2];
    const floatx4 fz = {0.f, 0.f, 0.f, 0.f};
    #pragma unroll
    for (int i = 0; i < 4; ++i) { acc[i][0] = fz; acc[i][1] = fz; }

    for (int s = 0; s < 96; ++s) {
        glds16(gAh + (size_t)s * 8192 + (2 * wv) * 1024,     L + (2 * wv) * 1024);
        glds16(gAh + (size_t)s * 8192 + (2 * wv + 1) * 1024, L + (2 * wv + 1) * 1024);
        glds16(gBh + (size_t)s * 4096 + wv * 1024,           L + 8192 + wv * 1024);
        __syncthreads();
        short8 ah[4], bh[2];
        #pragma unroll
        for (int i = 0; i < 4; ++i) ah[i] = *(const short8*)(L + afo[i]);
        #pragma unroll
        for (int j = 0; j < 2; ++j) bh[j] = *(const short8*)(L + 8192 + bfo[j]);
        #pragma unroll
        for (int i = 0; i < 4; ++i)
            #pragma unroll
            for (int j = 0; j < 2; ++j)
                acc[i][j] = __builtin_amdgcn_mfma_f32_16x16x32_bf16(ah[i], bh[j], acc[i][j], 0, 0, 0);
        __syncthreads();
    }
    #pragma unroll
    for (int i = 0; i < 4; ++i) {
        const int m0 = mt * 128 + wm * 64 + i * 16 + quad * 4;
        #pragma unroll
        for (int j = 0; j < 2; ++j) {
            const int n = nt * 64 + wn * 32 + j * 16 + lm;
            const float bv = bias[n];
            #pragma unroll
            for (int r = 0; r < 4; ++r) {
                const int mm = m0 + r;
                if (mm < 3136) outp[(size_t)mm * 2048 + n] = acc[i][j][r] + bv;
            }
        }
    }
}

// ================= y1 reduce (9 taps) + bias + relu =================
__global__ __launch_bounds__(256)
void y1_reduce(const float* __restrict__ y1p, const float* __restrict__ bias,
               float* __restrict__ y1)
{
    const int t = blockIdx.x * 256 + threadIdx.x;
    if (t >= 3136 * 128) return;
    const int n = t & 127;
    float s = bias[n];
    #pragma unroll
    for (int ks = 0; ks < 9; ++ks) s += y1p[(size_t)ks * 3136 * 128 + t];
    y1[t] = fmaxf(s, 0.f);
}

// ================= 1x1 tidy convs -> scores =================
__global__ __launch_bounds__(256)
void tidy(const float* __restrict__ in, const float* __restrict__ w,
          const float* __restrict__ bias, float* __restrict__ scores,
          int P, int nch, int off)
{
    const int wid = (blockIdx.x * 256 + threadIdx.x) >> 6;
    const int lane = threadIdx.x & 63;
    const int total = 16 * nch * P;
    if (wid >= total) return;
    const int pos = wid % P, ch = (wid / P) % nch, b = wid / (P * nch);
    const float* r = in + (size_t)(b * P + pos) * 128;
    const float* wr = w + ch * 128;
    float acc = r[lane] * wr[lane] + r[lane + 64] * wr[lane + 64];
    #pragma unroll
    for (int s = 32; s > 0; s >>= 1) acc += __shfl_down(acc, s, 64);
    if (lane == 0) scores[b * 1614 + off + ch * P + pos] = acc + bias[ch];
}

// ================= 3x3 stride-2 conv, wt layout [tap][ic][oc] =================
__global__ __launch_bounds__(256)
void conv_s2(const float* __restrict__ in, const float* __restrict__ wt,
             const float* __restrict__ bias, float* __restrict__ out,
             int Win, int Wout)
{
    const int t = blockIdx.x * 256 + threadIdx.x;
    const int oc = t & 127;
    const int pos = (t >> 7) % (Wout * Wout);
    const int b = t / (128 * Wout * Wout);
    if (b >= 16) return;
    const int oy = pos / Wout, ox = pos % Wout;
    float acc = bias[oc];
    for (int dy = 0; dy < 3; ++dy) {
        const int y = oy * 2 + dy - 1;
        if (y < 0 || y >= Win) continue;
        for (int dx = 0; dx < 3; ++dx) {
            const int x = ox * 2 + dx - 1;
            if (x < 0 || x >= Win) continue;
            const float* ip = in + (size_t)(b * Win * Win + y * Win + x) * 128;
            const float* wp = wt + (size_t)(dy * 3 + dx) * 16384 + oc;
            for (int ic = 0; ic < 128; ++ic)
                acc += ip[ic] * wp[ic * 128];
        }
    }
    out[(size_t)(b * Wout * Wout + pos) * 128 + oc] = fmaxf(acc, 0.f);
}

// ================= NMS =================
__global__ __launch_bounds__(256)
void nms(const float* __restrict__ scores, const int* __restrict__ anchors,
         int* __restrict__ top_idx)
{
    __shared__ float sc[1614];
    __shared__ unsigned char valid[1614];
    __shared__ float rv[256];
    __shared__ int ri[256];
    const int b = blockIdx.x, tid = threadIdx.x;
    for (int i = tid; i < 1614; i += 256) { sc[i] = scores[b * 1614 + i]; valid[i] = 1; }
    __syncthreads();
    for (int r = 0; r < 4; ++r) {
        float bv = -INFINITY; int bi = 0x7fffffff;
        for (int i = tid; i < 1614; i += 256) {
            const float v = valid[i] ? sc[i] : -INFINITY;
            if (v > bv || (v == bv && i < bi)) { bv = v; bi = i; }
        }
        rv[tid] = bv; ri[tid] = bi;
        __syncthreads();
        for (int s = 128; s > 0; s >>= 1) {
            if (tid < s) {
                const float v2 = rv[tid + s]; const int i2 = ri[tid + s];
                if (v2 > rv[tid] || (v2 == rv[tid] && i2 < ri[tid])) { rv[tid] = v2; ri[tid] = i2; }
            }
            __syncthreads();
        }
        const int pick = ri[0];
        if (tid == 0) top_idx[b * 4 + r] = pick;
        const float py0 = (float)anchors[pick * 4 + 0], px0 = (float)anchors[pick * 4 + 1];
        const float py1 = (float)anchors[pick * 4 + 2], px1 = (float)anchors[pick * 4 + 3];
        const float pa = (py1 - py0) * (px1 - px0);
        for (int i = tid; i < 1614; i += 256) {
            const float y0 = (float)anchors[i * 4 + 0], x0 = (float)anchors[i * 4 + 1];
            const float y1 = (float)anchors[i * 4 + 2], x1 = (float)anchors[i * 4 + 3];
            const float ih = fminf(y1, py1) - fmaxf(y0, py0);
            const float iw = fminf(x1, px1) - fmaxf(x0, px0);
            const float inter = (ih < 0.f || iw < 0.f) ? 0.f : ih * iw;
            const float area = (y1 - y0) * (x1 - x0);
            const float iou = inter / ((area + pa) - inter);
            if (iou >= 0.25f) valid[i] = 0;
        }
        __syncthreads();
    }
}

// ================= crop-resize -> partsw bf16 swizzled (8 px / thread) =================
__global__ __launch_bounds__(256)
void crop_resize(const float* __restrict__ x, const int* __restrict__ anchors,
                 const int* __restrict__ top_idx, ushort_t* __restrict__ psw)
{
    const int t = blockIdx.x * 256 + threadIdx.x;   // 1228800 total
    if (t >= 3200 * 384) return;
    const int m = t % 3200, k8 = t / 3200;
    const int mt = m >> 7, mr = m & 127, s = k8 >> 2, kg = k8 & 3;
    const size_t dst = (((size_t)(mt * 96 + s) * 4 + kg) * 128 + mr) * 8;
    short8 h;
    if (m >= 3136) {
        #pragma unroll
        for (int j = 0; j < 8; ++j) h[j] = 0;
        *(short8*)(psw + dst) = h;
        return;
    }
    const int q = m / 49, pos = m % 49, oy = pos / 7, ox = pos % 7;
    const int k = k8 * 8, c = k >> 10, r = (k >> 5) & 31, cc0 = k & 31;
    const int typ = oy * 32 + r;
    const int idx = top_idx[q];
    const int y0 = anchors[idx * 4 + 0], x0 = anchors[idx * 4 + 1];
    const int y1 = anchors[idx * 4 + 2], x1 = anchors[idx * 4 + 3];
    const float hh = (float)(y1 - y0), ww = (float)(x1 - x0);
    const float sy = (float)typ * (hh - 1.0f) / 223.0f;
    const float fy = floorf(sy);
    const float wy = sy - fy;
    const int iy0 = y0 + (int)fy;
    const int iy1 = min(iy0 + 1, y1 - 1);
    const float* xb = x + (size_t)((q >> 2) * 3 + c) * 200704;
    const int ry0 = iy0 - 224, ry1 = iy1 - 224;
    const bool vy0 = (ry0 >= 0 && ry0 < 448), vy1 = (ry1 >= 0 && ry1 < 448);
    const float* row0 = xb + (size_t)ry0 * 448;
    const float* row1 = xb + (size_t)ry1 * 448;
    #pragma unroll
    for (int j = 0; j < 8; ++j) {
        const int txp = ox * 32 + cc0 + j;
        const float sx = (float)txp * (ww - 1.0f) / 223.0f;
        const float fx = floorf(sx);
        const float wx = sx - fx;
        const int ix0 = x0 + (int)fx;
        const int ix1 = min(ix0 + 1, x1 - 1);
        const int rx0 = ix0 - 224, rx1 = ix1 - 224;
        const bool vx0 = (rx0 >= 0 && rx0 < 448), vx1 = (rx1 >= 0 && rx1 < 448);
        const float v00 = (vy0 && vx0) ? row0[rx0] : 0.f;
        const float v01 = (vy0 && vx1) ? row0[rx1] : 0.f;
        const float v10 = (vy1 && vx0) ? row1[rx0] : 0.f;
        const float v11 = (vy1 && vx1) ? row1[rx1] : 0.f;
        const float top = v00 * (1.f - wx) + v01 * wx;
        const float bot = v10 * (1.f - wx) + v11 * wx;
        h[j] = (short)f2bf(top * (1.f - wy) + bot * wy);
    }
    *(short8*)(psw + dst) = h;
}

// ================= means into concat =================
__global__ __launch_bounds__(256)
void part_mean(const float* __restrict__ pconv, float* __restrict__ concat)
{
    const int t = blockIdx.x * 256 + threadIdx.x;
    if (t >= 64 * 2048) return;
    const int n = t & 2047, q = t >> 11;
    float s = 0.f;
    for (int p = 0; p < 49; ++p) s += pconv[(size_t)(q * 49 + p) * 2048 + n];
    const int b = q >> 2, tt = q & 3;
    concat[(size_t)b * 10240 + tt * 2048 + n] = s / 49.f;
}

__global__ __launch_bounds__(256)
void raw_mean(const ushort_t* __restrict__ rh, const ushort_t* __restrict__ rl,
              float* __restrict__ concat)
{
    const int t = blockIdx.x * 256 + threadIdx.x;
    if (t >= 16 * 2048) return;
    const int n = t & 2047, b = t >> 11;
    float s = 0.f;
    for (int p = 0; p < 196; ++p) {
        const size_t o = (size_t)(b * 196 + p) * 2048 + n;
        s += bf2f(rh[o]) + bf2f(rl[o]);
    }
    concat[(size_t)b * 10240 + 8192 + n] = s / 196.f;
}

// ================= classifier =================
__global__ __launch_bounds__(256)
void classifier(const float* __restrict__ concat, const float* __restrict__ w,
                const float* __restrict__ bias, float* __restrict__ out)
{
    const int wid = (blockIdx.x * 256 + threadIdx.x) >> 6;
    const int lane = threadIdx.x & 63;
    if (wid >= 3200) return;
    const int cls = wid % 200, b = wid / 200;
    const float* cr = concat + (size_t)b * 10240;
    const float* wr = w + (size_t)cls * 10240;
    float acc = 0.f;
    for (int k = lane; k < 10240; k += 64) acc += cr[k] * wr[k];
    #pragma unroll
    for (int s = 32; s > 0; s >>= 1) acc += __shfl_down(acc, s, 64);
    if (lane == 0) out[b * 200 + cls] = acc + bias[cls];
}

extern "C" void kernel_launch(void* const* d_in, const int* in_sizes, int n_in,
                              void* d_out, int out_size, void* d_ws, size_t ws_size,
                              hipStream_t stream)
{
    const float* x     = (const float*)d_in[0];
    const float* bb_w  = (const float*)d_in[1];
    const float* bb_b  = (const float*)d_in[2];
    const float* n1_dw = (const float*)d_in[3];
    const float* n1_db = (const float*)d_in[4];
    const float* n1_tw = (const float*)d_in[5];
    const float* n1_tb = (const float*)d_in[6];
    const float* n2_dw = (const float*)d_in[7];
    const float* n2_db = (const float*)d_in[8];
    const float* n2_tw = (const float*)d_in[9];
    const float* n2_tb = (const float*)d_in[10];
    const float* n3_dw = (const float*)d_in[11];
    const float* n3_db = (const float*)d_in[12];
    const float* n3_tw = (const float*)d_in[13];
    const float* n3_tb = (const float*)d_in[14];
    const float* cn_w  = (const float*)d_in[15];
    const float* cn_b  = (const float*)d_in[16];
    const int*   anchors = (const int*)d_in[17];
    float* out = (float*)d_out;
    char* W = (char*)d_ws;

    ushort_t* bbwh  = (ushort_t*)(W + 0);
    ushort_t* bbwl  = (ushort_t*)(W + 12582912);
    float*    zpad  = (float*)(W + 25165824);
    int*      topidx= (int*)(W + 25166848);
    float*    scores= (float*)(W + 25167872);
    float*    y1    = (float*)(W + 25271296);
    float*    y2    = (float*)(W + 26876928);
    float*    y3    = (float*)(W + 27278336);
    float*    concat= (float*)(W + 27409408);
    char* E = W + 28064768;
    ushort_t* xh    = (ushort_t*)E;
    ushort_t* xl    = (ushort_t*)(E + 19660800);
    float*    y1p   = (float*)E;
    ushort_t* w1h   = (ushort_t*)(E + 14450688);
    ushort_t* w1l   = (ushort_t*)(E + 19169280);
    float*    wt2t  = (float*)(E + 23887872);
    float*    wt3t  = (float*)(E + 24477696);
    float*    pconv = (float*)E;
    char* F = W + 67386368;
    ushort_t* rawh  = (ushort_t*)F;
    ushort_t* rawl  = (ushort_t*)(F + 12845056);
    ushort_t* psw   = (ushort_t*)F;

    prep1<<<3072, 256, 0, stream>>>(bb_w, bbwh, bbwl, zpad);
    xconv<<<4800, 256, 0, stream>>>(x, xh, xl);

    gemm_x<<<dim3(32, 25), 256, 0, stream>>>(xh, xl, bbwh, bbwl, bb_b, rawh, rawl);

    prep2<<<2304, 256, 0, stream>>>(n1_dw, w1h, w1l, n2_dw, wt2t, n3_dw, wt3t);
    // raw_mean must run while rawh/rawl are still live (crop_resize clobbers F region)
    raw_mean<<<128, 256, 0, stream>>>(rawh, rawl, concat);

    gemm_nav<<<dim3(9, 49), 256, 0, stream>>>(rawh, rawl, w1h, w1l, (const char*)zpad, y1p);
    y1_reduce<<<1568, 256, 0, stream>>>(y1p, n1_db, y1);

    tidy<<<4704, 256, 0, stream>>>(y1, n1_tw, n1_tb, scores, 196, 6, 0);
    conv_s2<<<392, 256, 0, stream>>>(y1, wt2t, n2_db, y2, 14, 7);
    tidy<<<1176, 256, 0, stream>>>(y2, n2_tw, n2_tb, scores, 49, 6, 1176);
    conv_s2<<<128, 256, 0, stream>>>(y2, wt3t, n3_db, y3, 7, 4);
    tidy<<<576, 256, 0, stream>>>(y3, n3_tw, n3_tb, scores, 16, 9, 1470);

    nms<<<16, 256, 0, stream>>>(scores, anchors, topidx);
    crop_resize<<<4800, 256, 0, stream>>>(x, anchors, topidx, psw);

    gemm_part<<<dim3(32, 25), 256, 0, stream>>>(psw, bbwh, bb_b, pconv);
    part_mean<<<512, 256, 0, stream>>>(pconv, concat);
    classifier<<<800, 256, 0, stream>>>(concat, cn_w, cn_b, out);
}